// Round 11
// baseline (699.054 us; speedup 1.0000x reference)
//
#include <hip/hip_runtime.h>

using bf16 = __bf16;
using bf16x8 = __attribute__((ext_vector_type(8))) __bf16;
using bf16x4 = __attribute__((ext_vector_type(4))) __bf16;
using f32x4  = __attribute__((ext_vector_type(4))) float;

#define AS1(p) ((const __attribute__((address_space(1))) unsigned int*)(p))
#define AS3(p) ((__attribute__((address_space(3))) unsigned int*)(p))

template<int N> __device__ __forceinline__ void wait_vmcnt() {
    if constexpr (N == 0) asm volatile("s_waitcnt vmcnt(0)" ::: "memory");
    else if constexpr (N == 3) asm volatile("s_waitcnt vmcnt(3)" ::: "memory");
    else if constexpr (N == 4) asm volatile("s_waitcnt vmcnt(4)" ::: "memory");
    else if constexpr (N == 6) asm volatile("s_waitcnt vmcnt(6)" ::: "memory");
    else if constexpr (N == 8) asm volatile("s_waitcnt vmcnt(8)" ::: "memory");
}

// ---------------------------------------------------------------------------
// bf16 MFMA GEMM: C[M,N] = A[M,K] @ WT[N,K]^T (+ bias unless split-K)
// Tile TM x TN, BK=32, 256 threads (4 waves, 2x2), fragments 16x16x32.
// TRIPLE-buffered LDS, depth-2 counted-vmcnt pipeline, k-XOR LDS swizzle.
// EPI: 0 = +bias, bf16; 1 = +bias, GELU, bf16; 2 = +bias+PE, bf16 (embed);
//      3 = SPLIT-K2: blockIdx.y = K-half, write raw f32 partial (no bias) —
//          gets 1-blk/CU GEMMs to 2 blk/CU without shrinking tiles (R9 lesson)
// ---------------------------------------------------------------------------
template<int TM, int TN, int EPI>
__global__ __launch_bounds__(256, TM == 64 ? 4 : 3)
void gemm_kernel(const bf16* __restrict__ A, const bf16* __restrict__ WT,
                 const float* __restrict__ bias, bf16* __restrict__ Cbf,
                 float* __restrict__ Cpart, const float* __restrict__ PE,
                 int K, int ldc, int gx, int q8, int partOff)
{
    constexpr int NA  = TM / 16;      // A staging chunks (16 rows x 32 k = 1KB)
    constexpr int NCH = NA + TN / 16; // + B chunks
    constexpr int CPW = NCH / 4;      // chunks per wave (3 or 4)
    constexpr int MI  = TM / 32;      // row fragments per wave
    constexpr int NI  = TN / 32;      // col fragments per wave
    constexpr int ASZ = TM * 32;
    constexpr int BSZ = TN * 32;
    __shared__ bf16 Asm[3 * ASZ];
    __shared__ bf16 Bsm[3 * BSZ];
    const int tid = threadIdx.x;
    const int lane = tid & 63;
    const int w  = tid >> 6;          // wave id 0..3 (wave-uniform)
    const int wr = w >> 1, wc = w & 1;
    const int l4 = lane & 15, lg = lane >> 4;

    // XCD-bijective swizzle: consecutive swizzled ids land on one XCD.
    const int bid = blockIdx.x;
    const int s  = (bid & 7) * q8 + (bid >> 3);
    const int by = s / gx, bx = s - by * gx;
    const size_t m0 = (size_t)by * TM;
    const size_t n0 = (size_t)bx * TN;

    const int ks   = (EPI == 3) ? blockIdx.y : 0;
    const int Keff = (EPI == 3) ? (K >> 1) : K;
    const int kbase = ks * Keff;

    f32x4 acc[MI][NI] = {};

    // staging: chunk c<NA -> A rows c*16.., else B rows (c-NA)*16..
    // source k pre-swizzled so LDS [row][kgrp] holds global [row][kgrp^g(row)]
    const int lr  = lane >> 2;                              // within-chunk row
    const int ksw = (((lane & 3) ^ ((lane >> 3) & 3)) * 8); // swizzled k start
    const bf16* src[CPW];
    bf16* dst0[CPW];
    int step[CPW];
    #pragma unroll
    for (int ci = 0; ci < CPW; ++ci) {
        const int c = w * CPW + ci;
        if (c < NA) {
            src[ci]  = A + (m0 + (size_t)(c * 16 + lr)) * K + kbase + ksw;
            dst0[ci] = Asm + c * 512;
            step[ci] = ASZ;
        } else {
            src[ci]  = WT + (n0 + (size_t)((c - NA) * 16 + lr)) * K + kbase + ksw;
            dst0[ci] = Bsm + (c - NA) * 512;
            step[ci] = BSZ;
        }
    }
    // read side: same XOR (invariant under +16-row stride and wr/wc offsets)
    const int rsw = (lg ^ ((l4 >> 1) & 3)) * 8;
    const bf16* Ar = &Asm[(wr * (TM / 2) + l4) * 32 + rsw];
    const bf16* Br = &Bsm[(wc * (TN / 2) + l4) * 32 + rsw];

    auto STAGE = [&](int b) {
        #pragma unroll
        for (int ci = 0; ci < CPW; ++ci) {
            __builtin_amdgcn_global_load_lds(AS1(src[ci]),
                                             AS3(dst0[ci] + b * step[ci]), 16, 0, 0);
            src[ci] += 32;
        }
    };

    const int nt = Keff >> 5;
    STAGE(0);
    if (nt > 1) STAGE(1);

    int cur = 0;
    for (int t = 0; t < nt; ++t) {
        if (t + 2 < nt) {
            int pb = cur - 1; if (pb < 0) pb = 2;   // (cur+2)%3
            STAGE(pb);
            wait_vmcnt<2 * CPW>();   // tile t done; t+1,t+2 stay in flight
        } else if (t + 1 < nt) {
            wait_vmcnt<CPW>();
        } else {
            wait_vmcnt<0>();
        }
        __builtin_amdgcn_s_barrier();       // (A) buf[cur] visible to all
        const bf16* Ac = Ar + cur * ASZ;
        const bf16* Bc = Br + cur * BSZ;
        bf16x8 aF[MI], bF[NI];
        #pragma unroll
        for (int i = 0; i < MI; ++i) aF[i] = *(const bf16x8*)(Ac + i * 512);
        #pragma unroll
        for (int i = 0; i < NI; ++i) bF[i] = *(const bf16x8*)(Bc + i * 512);
        #pragma unroll
        for (int mi = 0; mi < MI; ++mi)
            #pragma unroll
            for (int ni = 0; ni < NI; ++ni)
                acc[mi][ni] = __builtin_amdgcn_mfma_f32_16x16x32_bf16(
                    aF[mi], bF[ni], acc[mi][ni], 0, 0, 0);
        asm volatile("s_waitcnt lgkmcnt(0)" ::: "memory");  // reads retired
        __builtin_amdgcn_s_barrier();       // (B) all reads of cur done
        cur = (cur == 2) ? 0 : cur + 1;
    }

    float* P = (EPI == 3) ? (Cpart + (size_t)ks * partOff) : nullptr;
    #pragma unroll
    for (int ni = 0; ni < NI; ++ni) {
        const int col = (int)n0 + wc * (TN / 2) + ni * 16 + l4;
        const float bv = (EPI == 3) ? 0.f : bias[col];
        #pragma unroll
        for (int mi = 0; mi < MI; ++mi) {
            const int row0 = (int)m0 + wr * (TM / 2) + mi * 16 + lg * 4;
            #pragma unroll
            for (int r = 0; r < 4; ++r) {
                float v = acc[mi][ni][r] + bv;
                const int row = row0 + r;
                if (EPI == 1) {
                    // GELU(tanh) == v * sigmoid(2*sqrt(2/pi)*(v+0.044715 v^3))
                    float u = 1.5957691216057308f * (v + 0.044715f * v * v * v);
                    v = v / (1.0f + __expf(-u));
                }
                if (EPI == 2) {
                    v += PE[((row & 511) << 9) + col];
                }
                if (EPI == 3) {
                    P[(size_t)row * ldc + col] = v;
                } else {
                    Cbf[(size_t)row * ldc + col] = (bf16)v;
                }
            }
        }
    }
}

// ---------------------------------------------------------------------------
// Fused band attention. Block = (ib: 64-row tile, bh: b*8+h). 256 thr, 4 waves.
// Wave w owns rows w*16..w*16+15 -> softmax fully wave-local.
// LDS: Ks unioned with Ps (Ks dead after QK^T; barrier closes the race) ->
// 53KB -> 3 blocks/CU. ctx staged through dead Vt for coalesced stores.
// qkv layout [4096][1536] (q|k|v each 512 cols). ctx layout [4096][512].
// WRITE_ATTN pass also zero-fills the out-of-band columns (replaces memset).
// ---------------------------------------------------------------------------
template<int WRITE_ATTN>
__global__ __launch_bounds__(256, 3)
void attn_kernel(const bf16* __restrict__ qkv, bf16* __restrict__ ctx,
                 float* __restrict__ attn_out /* already + l*2097152 */)
{
    __shared__ bf16 KPs[192 * 72];  // K rows stride 72; reused as P stride 200
    __shared__ bf16 Vt[64 * 200];   // V transposed [d][j]; reused for ctx tile
    bf16* Ks = KPs;
    bf16* Ps = KPs;                 // 64*200 = 12800 <= 13824 elems
    const int tid = threadIdx.x;
    const int lane = tid & 63, w = tid >> 6;
    const int l4 = lane & 15, lg = lane >> 4;
    const int bh = blockIdx.y, ib = blockIdx.x;
    const int b = bh >> 3, hd = bh & 7;
    const int i0 = ib * 64;
    const int j0 = (i0 >= 64) ? i0 - 64 : 0;
    const int j1 = (i0 + 128 <= 512) ? i0 + 128 : 512;
    const int W = j1 - j0;          // 128 or 192
    const size_t rowb = (size_t)b * 512;

    // zero out-of-band attention columns (replaces the global memset)
    if (WRITE_ATTN) {
        float* arow = attn_out + (size_t)b * 8388608 + (size_t)hd * 262144 +
                      (size_t)i0 * 512;
        const int zr = tid >> 2, p = tid & 3;
        f32x4 z = {0.f, 0.f, 0.f, 0.f};
        f32x4* rp = (f32x4*)(arow + (size_t)zr * 512);
        for (int c = p; c < (j0 >> 2); c += 4) rp[c] = z;
        for (int c = (j1 >> 2) + p; c < 128; c += 4) rp[c] = z;
    }

    // stage K rows [j0, j0+W)
    for (int it = 0; it < 6; ++it) {
        int chunk = tid + it * 256;                 // 0..1535
        int j = chunk >> 3, k0 = (chunk & 7) * 8;
        if (j < W) {
            bf16x8 v = *(const bf16x8*)(qkv + (rowb + j0 + j) * 1536 + 512 + hd * 64 + k0);
            *(bf16x8*)(&Ks[j * 72 + k0]) = v;
        }
    }
    // stage V transposed
    for (int it = 0; it < 6; ++it) {
        int chunk = tid + it * 256;
        int j = chunk >> 3, d0 = (chunk & 7) * 8;
        if (j < W) {
            bf16x8 v = *(const bf16x8*)(qkv + (rowb + j0 + j) * 1536 + 1024 + hd * 64 + d0);
            #pragma unroll
            for (int e = 0; e < 8; ++e) Vt[(d0 + e) * 200 + j] = v[e];
        }
    }
    // Q fragments for this wave's 16 rows, straight from global (L2-hot)
    bf16x8 qF0, qF1;
    {
        const bf16* qrow = qkv + (rowb + i0 + w * 16 + l4) * 1536 + hd * 64;
        qF0 = *(const bf16x8*)(qrow + lg * 8);
        qF1 = *(const bf16x8*)(qrow + 32 + lg * 8);
    }
    __syncthreads();

    // S = Q K^T / 8 over up to 12 col tiles
    f32x4 s[12];
    #pragma unroll
    for (int t = 0; t < 12; ++t) s[t] = (f32x4){0.f, 0.f, 0.f, 0.f};
    const int NT = W >> 4;
    __builtin_amdgcn_s_setprio(1);
    for (int t = 0; t < NT; ++t) {
        const bf16* kb = &Ks[(t * 16 + l4) * 72];
        bf16x8 b0 = *(const bf16x8*)(kb + lg * 8);
        bf16x8 b1 = *(const bf16x8*)(kb + 32 + lg * 8);
        s[t] = __builtin_amdgcn_mfma_f32_16x16x32_bf16(qF0, b0, s[t], 0, 0, 0);
        s[t] = __builtin_amdgcn_mfma_f32_16x16x32_bf16(qF1, b1, s[t], 0, 0, 0);
    }
    __builtin_amdgcn_s_setprio(0);
    // scale + band mask; row i = i0 + w*16 + lg*4 + r, col j = j0 + t*16 + l4
    const int irow0 = i0 + w * 16 + lg * 4;
    float pm[4] = {-3e38f, -3e38f, -3e38f, -3e38f};
    for (int t = 0; t < NT; ++t) {
        int jg = j0 + t * 16 + l4;
        #pragma unroll
        for (int r = 0; r < 4; ++r) {
            int dd = irow0 + r - jg;
            float sv = s[t][r] * 0.125f;
            if (dd > 64 || dd < -64) sv = -1e30f;
            s[t][r] = sv;
            pm[r] = fmaxf(pm[r], sv);
        }
    }
    #pragma unroll
    for (int d = 1; d < 16; d <<= 1)
        #pragma unroll
        for (int r = 0; r < 4; ++r) pm[r] = fmaxf(pm[r], __shfl_xor(pm[r], d));
    float ps[4] = {0.f, 0.f, 0.f, 0.f};
    for (int t = 0; t < NT; ++t)
        #pragma unroll
        for (int r = 0; r < 4; ++r) {
            float p = __expf(s[t][r] - pm[r]);
            s[t][r] = p;
            ps[r] += p;
        }
    #pragma unroll
    for (int d = 1; d < 16; d <<= 1)
        #pragma unroll
        for (int r = 0; r < 4; ++r) ps[r] += __shfl_xor(ps[r], d);
    float rinv[4];
    #pragma unroll
    for (int r = 0; r < 4; ++r) rinv[r] = 1.0f / ps[r];

    __syncthreads();    // all waves done reading Ks -> safe to write Ps union

    for (int t = 0; t < NT; ++t) {
        #pragma unroll
        for (int r = 0; r < 4; ++r) {
            float p = s[t][r] * rinv[r];
            Ps[(w * 16 + lg * 4 + r) * 200 + t * 16 + l4] = (bf16)p;
            if (WRITE_ATTN) {
                size_t off = (size_t)b * 8388608 + (size_t)hd * 262144 +
                             (size_t)(i0 + w * 16 + lg * 4 + r) * 512 +
                             (size_t)(j0 + t * 16 + l4);
                attn_out[off] = p;
            }
        }
    }
    // ctx = P @ V  (Ps rows are wave-private; compiler inserts lgkmcnt wait)
    f32x4 o[4] = {};
    const int KS = W >> 5;
    __builtin_amdgcn_s_setprio(1);
    for (int ks = 0; ks < KS; ++ks) {
        bf16x8 aF = *(const bf16x8*)(&Ps[(w * 16 + l4) * 200 + ks * 32 + lg * 8]);
        #pragma unroll
        for (int ni = 0; ni < 4; ++ni) {
            bf16x8 bF = *(const bf16x8*)(&Vt[(ni * 16 + l4) * 200 + ks * 32 + lg * 8]);
            o[ni] = __builtin_amdgcn_mfma_f32_16x16x32_bf16(aF, bF, o[ni], 0, 0, 0);
        }
    }
    __builtin_amdgcn_s_setprio(0);
    // stage ctx tile (64x64 bf16) into dead Vt, then coalesced bf16x8 stores
    __syncthreads();    // all waves done reading Vt/Ps
    bf16* Cs = Vt;
    #pragma unroll
    for (int ni = 0; ni < 4; ++ni)
        #pragma unroll
        for (int r = 0; r < 4; ++r)
            Cs[(w * 16 + lg * 4 + r) * 64 + ni * 16 + l4] = (bf16)o[ni][r];
    __syncthreads();
    #pragma unroll
    for (int it = 0; it < 2; ++it) {
        int chunk = tid + it * 256;
        int rl = chunk >> 3, c0 = (chunk & 7) << 3;
        *(bf16x8*)(&ctx[(rowb + i0 + rl) * 512 + hd * 64 + c0]) =
            *(const bf16x8*)(&Cs[rl * 64 + c0]);
    }
}

// ---------------------------------------------------------------------------
// LayerNorm(residual + y): wave per row (D=512, 8 elems/lane).
// SK=0: y from bf16 buffer. SK=1: y = p0 + p1 + bias (split-K reduction
// fused in; LN now sees f32 y — slightly better precision than bf16 tmp).
// hf!=nullptr -> final layer, write f32 output; else bf16 hbf (in-place ok).
// ---------------------------------------------------------------------------
template<int SK>
__global__ __launch_bounds__(256)
void ln_kernel(const bf16* __restrict__ y, const float* __restrict__ part,
               int partOff, const float* __restrict__ bias,
               const bf16* __restrict__ hin,
               const float* __restrict__ g, const float* __restrict__ bb,
               bf16* __restrict__ hbf, float* __restrict__ hf)
{
    const int row = blockIdx.x * 4 + (threadIdx.x >> 6);
    const int lane = threadIdx.x & 63;
    const size_t base = (size_t)row * 512 + lane * 8;
    const int c0 = lane * 8;
    bf16x8 hv = *(const bf16x8*)(hin + base);
    float x[8];
    if (SK) {
        f32x4 p00 = *(const f32x4*)(part + base);
        f32x4 p01 = *(const f32x4*)(part + base + 4);
        f32x4 p10 = *(const f32x4*)(part + partOff + base);
        f32x4 p11 = *(const f32x4*)(part + partOff + base + 4);
        f32x4 bi0 = *(const f32x4*)(bias + c0);
        f32x4 bi1 = *(const f32x4*)(bias + c0 + 4);
        #pragma unroll
        for (int i = 0; i < 8; ++i) {
            float yv = (i < 4) ? (p00[i] + p10[i] + bi0[i])
                               : (p01[i - 4] + p11[i - 4] + bi1[i - 4]);
            x[i] = yv + (float)hv[i];
        }
    } else {
        bf16x8 yv = *(const bf16x8*)(y + base);
        #pragma unroll
        for (int i = 0; i < 8; ++i) x[i] = (float)yv[i] + (float)hv[i];
    }
    float s = 0.f, q = 0.f;
    #pragma unroll
    for (int i = 0; i < 8; ++i) { s += x[i]; q += x[i] * x[i]; }
    #pragma unroll
    for (int d = 1; d < 64; d <<= 1) { s += __shfl_xor(s, d); q += __shfl_xor(q, d); }
    const float m = s * 0.001953125f;
    const float var = q * 0.001953125f - m * m;
    const float rstd = rsqrtf(var + 1e-5f);
    f32x4 g0 = *(const f32x4*)(g + c0), g1v = *(const f32x4*)(g + c0 + 4);
    f32x4 b0 = *(const f32x4*)(bb + c0), b1v = *(const f32x4*)(bb + c0 + 4);
    float o[8];
    #pragma unroll
    for (int i = 0; i < 8; ++i) {
        float gg = i < 4 ? g0[i] : g1v[i - 4];
        float bv = i < 4 ? b0[i] : b1v[i - 4];
        o[i] = (x[i] - m) * rstd * gg + bv;
    }
    if (hf) {
        f32x4 o0, o1;
        #pragma unroll
        for (int i = 0; i < 4; ++i) { o0[i] = o[i]; o1[i] = o[i + 4]; }
        *(f32x4*)(hf + base) = o0;
        *(f32x4*)(hf + base + 4) = o1;
    } else {
        bf16x8 ob;
        #pragma unroll
        for (int i = 0; i < 8; ++i) ob[i] = (bf16)o[i];
        *(bf16x8*)(hbf + base) = ob;
    }
}

// ---------------------------------------------------------------------------
// Weight transpose+convert: src f32 [K][N] -> dst bf16 [N][K] (32x32 LDS tiles)
// ---------------------------------------------------------------------------
struct TMat { const float* src; size_t dst; int K; int N; int tile0; };
struct TDesc { TMat m[26]; };

__global__ __launch_bounds__(256)
void wtrans_kernel(TDesc d, bf16* __restrict__ wbuf)
{
    __shared__ float tile[32][33];
    int t = blockIdx.x;
    int mi = 0;
    while (t >= d.m[mi + 1].tile0) ++mi;
    const TMat mm = d.m[mi];
    const int lt = t - mm.tile0;
    const int tpr = mm.N >> 5;
    const int kt = lt / tpr, nt = lt % tpr;
    const int r = threadIdx.x >> 5, c = threadIdx.x & 31;
    #pragma unroll
    for (int it = 0; it < 4; ++it)
        tile[r + it * 8][c] =
            mm.src[(size_t)(kt * 32 + r + it * 8) * mm.N + nt * 32 + c];
    __syncthreads();
    #pragma unroll
    for (int it = 0; it < 4; ++it)
        wbuf[mm.dst + (size_t)(nt * 32 + r + it * 8) * mm.K + kt * 32 + c] =
            (bf16)tile[c][r + it * 8];
}

// ---------------------------------------------------------------------------
// Fused prep: blocks 0-511 f2bf(x), 512-1023 PE table, 1024-1047 bias concat
// ---------------------------------------------------------------------------
__global__ void prep_kernel(const float* __restrict__ x, bf16* __restrict__ xbf,
                            float* __restrict__ pe,
                            const float* bq, const float* bk, const float* bv,
                            float* __restrict__ bqkv)
{
    const int bid = blockIdx.x;
    if (bid < 512) {
        int i = bid * 256 + threadIdx.x;       // 131072 vec4
        f32x4 v = *(const f32x4*)(x + (size_t)i * 4);
        bf16x4 o;
        #pragma unroll
        for (int e = 0; e < 4; ++e) o[e] = (bf16)v[e];
        *(bf16x4*)(xbf + (size_t)i * 4) = o;
    } else if (bid < 1024) {
        int i = (bid - 512) * 256 + threadIdx.x;   // 131072 (s,d2) pairs
        int s = i >> 8, d2 = i & 255;
        float ang = (float)s * expf((float)(2 * d2) * -0.017988946039016f);
        pe[(s << 9) + 2 * d2]     = sinf(ang);
        pe[(s << 9) + 2 * d2 + 1] = cosf(ang);
    } else {
        int i = (bid - 1024) * 256 + threadIdx.x;  // 6144
        if (i < 6144) {
            int l = i / 1536, c = i - l * 1536;
            float v;
            if (c < 512) v = bq[l * 512 + c];
            else if (c < 1024) v = bk[l * 512 + c - 512];
            else v = bv[l * 512 + c - 1024];
            bqkv[i] = v;
        }
    }
}

// ---------------------------------------------------------------------------
extern "C" void kernel_launch(void* const* d_in, const int* in_sizes, int n_in,
                              void* d_out, int out_size, void* d_ws, size_t ws_size,
                              hipStream_t stream)
{
    const float* x   = (const float*)d_in[0];
    const float* We  = (const float*)d_in[1];
    const float* be  = (const float*)d_in[2];
    const float* Wq  = (const float*)d_in[3];
    const float* bq  = (const float*)d_in[4];
    const float* Wk  = (const float*)d_in[5];
    const float* bk  = (const float*)d_in[6];
    const float* Wv  = (const float*)d_in[7];
    const float* bv  = (const float*)d_in[8];
    const float* Wo  = (const float*)d_in[9];
    const float* bo  = (const float*)d_in[10];
    const float* g1  = (const float*)d_in[11];
    const float* b1n = (const float*)d_in[12];
    const float* W1  = (const float*)d_in[13];
    const float* b1f = (const float*)d_in[14];
    const float* W2  = (const float*)d_in[15];
    const float* b2f = (const float*)d_in[16];
    const float* g2  = (const float*)d_in[17];
    const float* b2n = (const float*)d_in[18];

    char* ws = (char*)d_ws;
    bf16* wbuf = (bf16*)ws;
    size_t off = 12648448ull * 2;                       // transposed bf16 weights
    float* bqkv = (float*)(ws + off); off += 6144ull * 4;
    float* pe   = (float*)(ws + off); off += 262144ull * 4;
    bf16* xbf   = (bf16*)(ws + off);  off += 524288ull * 2;
    bf16* hbf   = (bf16*)(ws + off);  off += 2097152ull * 2;
    bf16* qkvb  = (bf16*)(ws + off);  off += 6291456ull * 2;
    bf16* ctx   = (bf16*)(ws + off);  off += 2097152ull * 2;
    float* part = (float*)(ws + off); off += 4194304ull * 4;  // 2x f32 partials
    bf16* ffn   = (bf16*)(ws + off);  off += 8388608ull * 2;
    (void)ws_size; (void)in_sizes; (void)n_in; (void)out_size;

    float* out_h = (float*)d_out;
    float* out_attn = out_h + 2097152;

    TDesc td{};
    int tile = 0, e = 0;
    auto add = [&](const float* src, size_t dst, int K, int N) {
        td.m[e].src = src; td.m[e].dst = dst; td.m[e].K = K; td.m[e].N = N;
        td.m[e].tile0 = tile; tile += (K >> 5) * (N >> 5); ++e;
    };
    add(We, 0, 128, 512);
    for (int l = 0; l < 4; ++l) {
        size_t base = 65536 + (size_t)l * 3145728;
        add(Wq + (size_t)l * 262144,  base + 0,       512, 512);
        add(Wk + (size_t)l * 262144,  base + 262144,  512, 512);
        add(Wv + (size_t)l * 262144,  base + 524288,  512, 512);
        add(Wo + (size_t)l * 262144,  base + 786432,  512, 512);
        add(W1 + (size_t)l * 1048576, base + 1048576, 512, 2048);
        add(W2 + (size_t)l * 1048576, base + 2097152, 2048, 512);
    }
    td.m[e].tile0 = tile;  // sentinel (e == 25)

    wtrans_kernel<<<dim3(tile), dim3(256), 0, stream>>>(td, wbuf);
    prep_kernel<<<dim3(1048), dim3(256), 0, stream>>>(x, xbf, pe, bq, bk, bv, bqkv);

    // embed: hbf = bf16(x @ We + be + PE)
    gemm_kernel<64, 128, 2><<<dim3(256), dim3(256), 0, stream>>>(
        xbf, wbuf, be, hbf, (float*)nullptr, pe, 128, 512, 4, 32, 0);

    for (int l = 0; l < 4; ++l) {
        const bf16* WqkvT = wbuf + 65536 + (size_t)l * 3145728;
        const bf16* WoT   = WqkvT + 786432;
        const bf16* W1T   = WqkvT + 1048576;
        const bf16* W2T   = WqkvT + 2097152;
        for (int pass = 0; pass < 2; ++pass) {
            gemm_kernel<128, 128, 0><<<dim3(384), dim3(256), 0, stream>>>(
                hbf, WqkvT, bqkv + l * 1536, qkvb, (float*)nullptr, (float*)nullptr,
                512, 1536, 12, 48, 0);
            if (pass == 0)
                attn_kernel<0><<<dim3(8, 64), dim3(256), 0, stream>>>(
                    qkvb, ctx, (float*)nullptr);
            else
                attn_kernel<1><<<dim3(8, 64), dim3(256), 0, stream>>>(
                    qkvb, ctx, out_attn + (size_t)l * 2097152);
            // Wo split-K2: grid (256,2) -> 2 blk/CU, f32 partials
            gemm_kernel<64, 128, 3><<<dim3(256, 2), dim3(256), 0, stream>>>(
                ctx, WoT, (float*)nullptr, (bf16*)nullptr, part, (float*)nullptr,
                512, 512, 4, 32, 2097152);
            ln_kernel<1><<<dim3(1024), dim3(256), 0, stream>>>(
                (bf16*)nullptr, part, 2097152, bo + l * 512, hbf,
                g1 + l * 512, b1n + l * 512, hbf, (float*)nullptr);
        }
        gemm_kernel<128, 128, 1><<<dim3(512), dim3(256), 0, stream>>>(
            hbf, W1T, b1f + l * 2048, ffn, (float*)nullptr, (float*)nullptr,
            512, 2048, 16, 64, 0);
        // FFN2 split-K2: grid (256,2) -> 2 blk/CU, f32 partials
        gemm_kernel<64, 128, 3><<<dim3(256, 2), dim3(256), 0, stream>>>(
            ffn, W2T, (float*)nullptr, (bf16*)nullptr, part, (float*)nullptr,
            2048, 512, 4, 32, 2097152);
        ln_kernel<1><<<dim3(1024), dim3(256), 0, stream>>>(
            (bf16*)nullptr, part, 2097152, b2f + l * 512, hbf,
            g2 + l * 512, b2n + l * 512, hbf,
            (l == 3) ? out_h : (float*)nullptr);
    }
}

// Round 12
// 680.668 us; speedup vs baseline: 1.0270x; 1.0270x over previous
//
#include <hip/hip_runtime.h>

using bf16 = __bf16;
using bf16x8 = __attribute__((ext_vector_type(8))) __bf16;
using bf16x4 = __attribute__((ext_vector_type(4))) __bf16;
using f32x4  = __attribute__((ext_vector_type(4))) float;

#define AS1(p) ((const __attribute__((address_space(1))) unsigned int*)(p))
#define AS3(p) ((__attribute__((address_space(3))) unsigned int*)(p))

template<int N> __device__ __forceinline__ void wait_vmcnt() {
    if constexpr (N == 0) asm volatile("s_waitcnt vmcnt(0)" ::: "memory");
    else if constexpr (N == 3) asm volatile("s_waitcnt vmcnt(3)" ::: "memory");
    else if constexpr (N == 4) asm volatile("s_waitcnt vmcnt(4)" ::: "memory");
    else if constexpr (N == 6) asm volatile("s_waitcnt vmcnt(6)" ::: "memory");
    else if constexpr (N == 8) asm volatile("s_waitcnt vmcnt(8)" ::: "memory");
}

// ---------------------------------------------------------------------------
// bf16 MFMA GEMM: C[M,N] = A[M,K] @ WT[N,K]^T + bias
// Tile TM x TN, BK=32, 256 threads (4 waves, 2x2), fragments 16x16x32.
// TRIPLE-buffered LDS, depth-2 counted-vmcnt pipeline, k-XOR LDS swizzle.
// R12: qkv retiled 128x128 -> 64x192 (grid 384 -> 512 = even 2 blk/CU;
// fixes the 2:1 block imbalance). Split-K (R11) reverted: halving the
// 16-step K-loop amputates the pipeline and fattens the epilogue.
// EPI: 0 = +bias, bf16; 1 = +bias, GELU, bf16; 2 = +bias+PE, bf16 (embed)
// ---------------------------------------------------------------------------
template<int TM, int TN, int EPI>
__global__ __launch_bounds__(256, TM == 64 ? 4 : 3)
void gemm_kernel(const bf16* __restrict__ A, const bf16* __restrict__ WT,
                 const float* __restrict__ bias, bf16* __restrict__ Cbf,
                 const float* __restrict__ PE,
                 int K, int ldc, int gx, int q8)
{
    constexpr int NA  = TM / 16;      // A staging chunks (16 rows x 32 k = 1KB)
    constexpr int NCH = NA + TN / 16; // + B chunks
    constexpr int CPW = NCH / 4;      // chunks per wave (3 or 4)
    constexpr int MI  = TM / 32;      // row fragments per wave
    constexpr int NI  = TN / 32;      // col fragments per wave
    constexpr int ASZ = TM * 32;
    constexpr int BSZ = TN * 32;
    __shared__ bf16 Asm[3 * ASZ];
    __shared__ bf16 Bsm[3 * BSZ];
    const int tid = threadIdx.x;
    const int lane = tid & 63;
    const int w  = tid >> 6;          // wave id 0..3 (wave-uniform)
    const int wr = w >> 1, wc = w & 1;
    const int l4 = lane & 15, lg = lane >> 4;

    // XCD-bijective swizzle: consecutive swizzled ids land on one XCD.
    const int bid = blockIdx.x;
    const int s  = (bid & 7) * q8 + (bid >> 3);
    const int by = s / gx, bx = s - by * gx;
    const size_t m0 = (size_t)by * TM;
    const size_t n0 = (size_t)bx * TN;

    f32x4 acc[MI][NI] = {};

    // staging: chunk c<NA -> A rows c*16.., else B rows (c-NA)*16..
    // source k pre-swizzled so LDS [row][kgrp] holds global [row][kgrp^g(row)]
    const int lr  = lane >> 2;                              // within-chunk row
    const int ksw = (((lane & 3) ^ ((lane >> 3) & 3)) * 8); // swizzled k start
    const bf16* src[CPW];
    bf16* dst0[CPW];
    int step[CPW];
    #pragma unroll
    for (int ci = 0; ci < CPW; ++ci) {
        const int c = w * CPW + ci;
        if (c < NA) {
            src[ci]  = A + (m0 + (size_t)(c * 16 + lr)) * K + ksw;
            dst0[ci] = Asm + c * 512;
            step[ci] = ASZ;
        } else {
            src[ci]  = WT + (n0 + (size_t)((c - NA) * 16 + lr)) * K + ksw;
            dst0[ci] = Bsm + (c - NA) * 512;
            step[ci] = BSZ;
        }
    }
    // read side: same XOR (invariant under +16-row stride and wr/wc offsets)
    const int rsw = (lg ^ ((l4 >> 1) & 3)) * 8;
    const bf16* Ar = &Asm[(wr * (TM / 2) + l4) * 32 + rsw];
    const bf16* Br = &Bsm[(wc * (TN / 2) + l4) * 32 + rsw];

    auto STAGE = [&](int b) {
        #pragma unroll
        for (int ci = 0; ci < CPW; ++ci) {
            __builtin_amdgcn_global_load_lds(AS1(src[ci]),
                                             AS3(dst0[ci] + b * step[ci]), 16, 0, 0);
            src[ci] += 32;
        }
    };

    const int nt = K >> 5;
    STAGE(0);
    if (nt > 1) STAGE(1);

    int cur = 0;
    for (int t = 0; t < nt; ++t) {
        if (t + 2 < nt) {
            int pb = cur - 1; if (pb < 0) pb = 2;   // (cur+2)%3
            STAGE(pb);
            wait_vmcnt<2 * CPW>();   // tile t done; t+1,t+2 stay in flight
        } else if (t + 1 < nt) {
            wait_vmcnt<CPW>();
        } else {
            wait_vmcnt<0>();
        }
        __builtin_amdgcn_s_barrier();       // (A) buf[cur] visible to all
        const bf16* Ac = Ar + cur * ASZ;
        const bf16* Bc = Br + cur * BSZ;
        bf16x8 aF[MI], bF[NI];
        #pragma unroll
        for (int i = 0; i < MI; ++i) aF[i] = *(const bf16x8*)(Ac + i * 512);
        #pragma unroll
        for (int i = 0; i < NI; ++i) bF[i] = *(const bf16x8*)(Bc + i * 512);
        #pragma unroll
        for (int mi = 0; mi < MI; ++mi)
            #pragma unroll
            for (int ni = 0; ni < NI; ++ni)
                acc[mi][ni] = __builtin_amdgcn_mfma_f32_16x16x32_bf16(
                    aF[mi], bF[ni], acc[mi][ni], 0, 0, 0);
        asm volatile("s_waitcnt lgkmcnt(0)" ::: "memory");  // reads retired
        __builtin_amdgcn_s_barrier();       // (B) all reads of cur done
        cur = (cur == 2) ? 0 : cur + 1;
    }

    #pragma unroll
    for (int ni = 0; ni < NI; ++ni) {
        const int col = (int)n0 + wc * (TN / 2) + ni * 16 + l4;
        const float bv = bias[col];
        #pragma unroll
        for (int mi = 0; mi < MI; ++mi) {
            const int row0 = (int)m0 + wr * (TM / 2) + mi * 16 + lg * 4;
            #pragma unroll
            for (int r = 0; r < 4; ++r) {
                float v = acc[mi][ni][r] + bv;
                const int row = row0 + r;
                if (EPI == 1) {
                    // GELU(tanh) == v * sigmoid(2*sqrt(2/pi)*(v+0.044715 v^3))
                    float u = 1.5957691216057308f * (v + 0.044715f * v * v * v);
                    v = v / (1.0f + __expf(-u));
                }
                if (EPI == 2) {
                    v += PE[((row & 511) << 9) + col];
                }
                Cbf[(size_t)row * ldc + col] = (bf16)v;
            }
        }
    }
}

// ---------------------------------------------------------------------------
// Fused band attention. Block = (ib: 64-row tile, bh: b*8+h). 256 thr, 4 waves.
// Wave w owns rows w*16..w*16+15 -> softmax fully wave-local.
// LDS: Ks unioned with Ps (Ks dead after QK^T; barrier closes the race) ->
// 53KB -> 3 blocks/CU. ctx staged through dead Vt for coalesced stores.
// qkv layout [4096][1536] (q|k|v each 512 cols). ctx layout [4096][512].
// WRITE_ATTN pass also zero-fills the out-of-band columns (replaces memset).
// ---------------------------------------------------------------------------
template<int WRITE_ATTN>
__global__ __launch_bounds__(256, 3)
void attn_kernel(const bf16* __restrict__ qkv, bf16* __restrict__ ctx,
                 float* __restrict__ attn_out /* already + l*2097152 */)
{
    __shared__ bf16 KPs[192 * 72];  // K rows stride 72; reused as P stride 200
    __shared__ bf16 Vt[64 * 200];   // V transposed [d][j]; reused for ctx tile
    bf16* Ks = KPs;
    bf16* Ps = KPs;                 // 64*200 = 12800 <= 13824 elems
    const int tid = threadIdx.x;
    const int lane = tid & 63, w = tid >> 6;
    const int l4 = lane & 15, lg = lane >> 4;
    const int bh = blockIdx.y, ib = blockIdx.x;
    const int b = bh >> 3, hd = bh & 7;
    const int i0 = ib * 64;
    const int j0 = (i0 >= 64) ? i0 - 64 : 0;
    const int j1 = (i0 + 128 <= 512) ? i0 + 128 : 512;
    const int W = j1 - j0;          // 128 or 192
    const size_t rowb = (size_t)b * 512;

    // zero out-of-band attention columns (replaces the global memset)
    if (WRITE_ATTN) {
        float* arow = attn_out + (size_t)b * 8388608 + (size_t)hd * 262144 +
                      (size_t)i0 * 512;
        const int zr = tid >> 2, p = tid & 3;
        f32x4 z = {0.f, 0.f, 0.f, 0.f};
        f32x4* rp = (f32x4*)(arow + (size_t)zr * 512);
        for (int c = p; c < (j0 >> 2); c += 4) rp[c] = z;
        for (int c = (j1 >> 2) + p; c < 128; c += 4) rp[c] = z;
    }

    // stage K rows [j0, j0+W)
    for (int it = 0; it < 6; ++it) {
        int chunk = tid + it * 256;                 // 0..1535
        int j = chunk >> 3, k0 = (chunk & 7) * 8;
        if (j < W) {
            bf16x8 v = *(const bf16x8*)(qkv + (rowb + j0 + j) * 1536 + 512 + hd * 64 + k0);
            *(bf16x8*)(&Ks[j * 72 + k0]) = v;
        }
    }
    // stage V transposed
    for (int it = 0; it < 6; ++it) {
        int chunk = tid + it * 256;
        int j = chunk >> 3, d0 = (chunk & 7) * 8;
        if (j < W) {
            bf16x8 v = *(const bf16x8*)(qkv + (rowb + j0 + j) * 1536 + 1024 + hd * 64 + d0);
            #pragma unroll
            for (int e = 0; e < 8; ++e) Vt[(d0 + e) * 200 + j] = v[e];
        }
    }
    // Q fragments for this wave's 16 rows, straight from global (L2-hot)
    bf16x8 qF0, qF1;
    {
        const bf16* qrow = qkv + (rowb + i0 + w * 16 + l4) * 1536 + hd * 64;
        qF0 = *(const bf16x8*)(qrow + lg * 8);
        qF1 = *(const bf16x8*)(qrow + 32 + lg * 8);
    }
    __syncthreads();

    // S = Q K^T / 8 over up to 12 col tiles
    f32x4 s[12];
    #pragma unroll
    for (int t = 0; t < 12; ++t) s[t] = (f32x4){0.f, 0.f, 0.f, 0.f};
    const int NT = W >> 4;
    __builtin_amdgcn_s_setprio(1);
    for (int t = 0; t < NT; ++t) {
        const bf16* kb = &Ks[(t * 16 + l4) * 72];
        bf16x8 b0 = *(const bf16x8*)(kb + lg * 8);
        bf16x8 b1 = *(const bf16x8*)(kb + 32 + lg * 8);
        s[t] = __builtin_amdgcn_mfma_f32_16x16x32_bf16(qF0, b0, s[t], 0, 0, 0);
        s[t] = __builtin_amdgcn_mfma_f32_16x16x32_bf16(qF1, b1, s[t], 0, 0, 0);
    }
    __builtin_amdgcn_s_setprio(0);
    // scale + band mask; row i = i0 + w*16 + lg*4 + r, col j = j0 + t*16 + l4
    const int irow0 = i0 + w * 16 + lg * 4;
    float pm[4] = {-3e38f, -3e38f, -3e38f, -3e38f};
    for (int t = 0; t < NT; ++t) {
        int jg = j0 + t * 16 + l4;
        #pragma unroll
        for (int r = 0; r < 4; ++r) {
            int dd = irow0 + r - jg;
            float sv = s[t][r] * 0.125f;
            if (dd > 64 || dd < -64) sv = -1e30f;
            s[t][r] = sv;
            pm[r] = fmaxf(pm[r], sv);
        }
    }
    #pragma unroll
    for (int d = 1; d < 16; d <<= 1)
        #pragma unroll
        for (int r = 0; r < 4; ++r) pm[r] = fmaxf(pm[r], __shfl_xor(pm[r], d));
    float ps[4] = {0.f, 0.f, 0.f, 0.f};
    for (int t = 0; t < NT; ++t)
        #pragma unroll
        for (int r = 0; r < 4; ++r) {
            float p = __expf(s[t][r] - pm[r]);
            s[t][r] = p;
            ps[r] += p;
        }
    #pragma unroll
    for (int d = 1; d < 16; d <<= 1)
        #pragma unroll
        for (int r = 0; r < 4; ++r) ps[r] += __shfl_xor(ps[r], d);
    float rinv[4];
    #pragma unroll
    for (int r = 0; r < 4; ++r) rinv[r] = 1.0f / ps[r];

    __syncthreads();    // all waves done reading Ks -> safe to write Ps union

    for (int t = 0; t < NT; ++t) {
        #pragma unroll
        for (int r = 0; r < 4; ++r) {
            float p = s[t][r] * rinv[r];
            Ps[(w * 16 + lg * 4 + r) * 200 + t * 16 + l4] = (bf16)p;
            if (WRITE_ATTN) {
                size_t off = (size_t)b * 8388608 + (size_t)hd * 262144 +
                             (size_t)(i0 + w * 16 + lg * 4 + r) * 512 +
                             (size_t)(j0 + t * 16 + l4);
                attn_out[off] = p;
            }
        }
    }
    // ctx = P @ V  (Ps rows are wave-private; compiler inserts lgkmcnt wait)
    f32x4 o[4] = {};
    const int KS = W >> 5;
    __builtin_amdgcn_s_setprio(1);
    for (int ks = 0; ks < KS; ++ks) {
        bf16x8 aF = *(const bf16x8*)(&Ps[(w * 16 + l4) * 200 + ks * 32 + lg * 8]);
        #pragma unroll
        for (int ni = 0; ni < 4; ++ni) {
            bf16x8 bF = *(const bf16x8*)(&Vt[(ni * 16 + l4) * 200 + ks * 32 + lg * 8]);
            o[ni] = __builtin_amdgcn_mfma_f32_16x16x32_bf16(aF, bF, o[ni], 0, 0, 0);
        }
    }
    __builtin_amdgcn_s_setprio(0);
    // stage ctx tile (64x64 bf16) into dead Vt, then coalesced bf16x8 stores
    __syncthreads();    // all waves done reading Vt/Ps
    bf16* Cs = Vt;
    #pragma unroll
    for (int ni = 0; ni < 4; ++ni)
        #pragma unroll
        for (int r = 0; r < 4; ++r)
            Cs[(w * 16 + lg * 4 + r) * 64 + ni * 16 + l4] = (bf16)o[ni][r];
    __syncthreads();
    #pragma unroll
    for (int it = 0; it < 2; ++it) {
        int chunk = tid + it * 256;
        int rl = chunk >> 3, c0 = (chunk & 7) << 3;
        *(bf16x8*)(&ctx[(rowb + i0 + rl) * 512 + hd * 64 + c0]) =
            *(const bf16x8*)(&Cs[rl * 64 + c0]);
    }
}

// ---------------------------------------------------------------------------
// LayerNorm(residual + y): wave per row (D=512, 8 elems/lane).
// Residual stream is bf16-only (stats/normalization still f32 in-reg).
// hf==nullptr -> write bf16 hbf (in-place safe, block owns its rows);
// hf!=nullptr -> final layer, write f32 output only.
// ---------------------------------------------------------------------------
__global__ __launch_bounds__(256)
void ln_kernel(const bf16* __restrict__ y, const bf16* __restrict__ hin,
               const float* __restrict__ g, const float* __restrict__ bb,
               bf16* __restrict__ hbf, float* __restrict__ hf)
{
    const int row = blockIdx.x * 4 + (threadIdx.x >> 6);
    const int lane = threadIdx.x & 63;
    const size_t base = (size_t)row * 512 + lane * 8;
    bf16x8 yv = *(const bf16x8*)(y + base);
    bf16x8 hv = *(const bf16x8*)(hin + base);
    float x[8];
    #pragma unroll
    for (int i = 0; i < 8; ++i) x[i] = (float)yv[i] + (float)hv[i];
    float s = 0.f, q = 0.f;
    #pragma unroll
    for (int i = 0; i < 8; ++i) { s += x[i]; q += x[i] * x[i]; }
    #pragma unroll
    for (int d = 1; d < 64; d <<= 1) { s += __shfl_xor(s, d); q += __shfl_xor(q, d); }
    const float m = s * 0.001953125f;
    const float var = q * 0.001953125f - m * m;
    const float rstd = rsqrtf(var + 1e-5f);
    const int c0 = lane * 8;
    f32x4 g0 = *(const f32x4*)(g + c0), g1v = *(const f32x4*)(g + c0 + 4);
    f32x4 b0 = *(const f32x4*)(bb + c0), b1v = *(const f32x4*)(bb + c0 + 4);
    float o[8];
    #pragma unroll
    for (int i = 0; i < 8; ++i) {
        float gg = i < 4 ? g0[i] : g1v[i - 4];
        float bv = i < 4 ? b0[i] : b1v[i - 4];
        o[i] = (x[i] - m) * rstd * gg + bv;
    }
    if (hf) {
        f32x4 o0, o1;
        #pragma unroll
        for (int i = 0; i < 4; ++i) { o0[i] = o[i]; o1[i] = o[i + 4]; }
        *(f32x4*)(hf + base) = o0;
        *(f32x4*)(hf + base + 4) = o1;
    } else {
        bf16x8 ob;
        #pragma unroll
        for (int i = 0; i < 8; ++i) ob[i] = (bf16)o[i];
        *(bf16x8*)(hbf + base) = ob;
    }
}

// ---------------------------------------------------------------------------
// Weight transpose+convert: src f32 [K][N] -> dst bf16 [N][K] (32x32 LDS tiles)
// ---------------------------------------------------------------------------
struct TMat { const float* src; size_t dst; int K; int N; int tile0; };
struct TDesc { TMat m[26]; };

__global__ __launch_bounds__(256)
void wtrans_kernel(TDesc d, bf16* __restrict__ wbuf)
{
    __shared__ float tile[32][33];
    int t = blockIdx.x;
    int mi = 0;
    while (t >= d.m[mi + 1].tile0) ++mi;
    const TMat mm = d.m[mi];
    const int lt = t - mm.tile0;
    const int tpr = mm.N >> 5;
    const int kt = lt / tpr, nt = lt % tpr;
    const int r = threadIdx.x >> 5, c = threadIdx.x & 31;
    #pragma unroll
    for (int it = 0; it < 4; ++it)
        tile[r + it * 8][c] =
            mm.src[(size_t)(kt * 32 + r + it * 8) * mm.N + nt * 32 + c];
    __syncthreads();
    #pragma unroll
    for (int it = 0; it < 4; ++it)
        wbuf[mm.dst + (size_t)(nt * 32 + r + it * 8) * mm.K + kt * 32 + c] =
            (bf16)tile[c][r + it * 8];
}

// ---------------------------------------------------------------------------
// Fused prep: blocks 0-511 f2bf(x), 512-1023 PE table, 1024-1047 bias concat
// ---------------------------------------------------------------------------
__global__ void prep_kernel(const float* __restrict__ x, bf16* __restrict__ xbf,
                            float* __restrict__ pe,
                            const float* bq, const float* bk, const float* bv,
                            float* __restrict__ bqkv)
{
    const int bid = blockIdx.x;
    if (bid < 512) {
        int i = bid * 256 + threadIdx.x;       // 131072 vec4
        f32x4 v = *(const f32x4*)(x + (size_t)i * 4);
        bf16x4 o;
        #pragma unroll
        for (int e = 0; e < 4; ++e) o[e] = (bf16)v[e];
        *(bf16x4*)(xbf + (size_t)i * 4) = o;
    } else if (bid < 1024) {
        int i = (bid - 512) * 256 + threadIdx.x;   // 131072 (s,d2) pairs
        int s = i >> 8, d2 = i & 255;
        float ang = (float)s * expf((float)(2 * d2) * -0.017988946039016f);
        pe[(s << 9) + 2 * d2]     = sinf(ang);
        pe[(s << 9) + 2 * d2 + 1] = cosf(ang);
    } else {
        int i = (bid - 1024) * 256 + threadIdx.x;  // 6144
        if (i < 6144) {
            int l = i / 1536, c = i - l * 1536;
            float v;
            if (c < 512) v = bq[l * 512 + c];
            else if (c < 1024) v = bk[l * 512 + c - 512];
            else v = bv[l * 512 + c - 1024];
            bqkv[i] = v;
        }
    }
}

// ---------------------------------------------------------------------------
extern "C" void kernel_launch(void* const* d_in, const int* in_sizes, int n_in,
                              void* d_out, int out_size, void* d_ws, size_t ws_size,
                              hipStream_t stream)
{
    const float* x   = (const float*)d_in[0];
    const float* We  = (const float*)d_in[1];
    const float* be  = (const float*)d_in[2];
    const float* Wq  = (const float*)d_in[3];
    const float* bq  = (const float*)d_in[4];
    const float* Wk  = (const float*)d_in[5];
    const float* bk  = (const float*)d_in[6];
    const float* Wv  = (const float*)d_in[7];
    const float* bv  = (const float*)d_in[8];
    const float* Wo  = (const float*)d_in[9];
    const float* bo  = (const float*)d_in[10];
    const float* g1  = (const float*)d_in[11];
    const float* b1n = (const float*)d_in[12];
    const float* W1  = (const float*)d_in[13];
    const float* b1f = (const float*)d_in[14];
    const float* W2  = (const float*)d_in[15];
    const float* b2f = (const float*)d_in[16];
    const float* g2  = (const float*)d_in[17];
    const float* b2n = (const float*)d_in[18];

    char* ws = (char*)d_ws;
    bf16* wbuf = (bf16*)ws;
    size_t off = 12648448ull * 2;                       // transposed bf16 weights
    float* bqkv = (float*)(ws + off); off += 6144ull * 4;
    float* pe   = (float*)(ws + off); off += 262144ull * 4;
    bf16* xbf   = (bf16*)(ws + off);  off += 524288ull * 2;
    bf16* hbf   = (bf16*)(ws + off);  off += 2097152ull * 2;
    bf16* qkvb  = (bf16*)(ws + off);  off += 6291456ull * 2;
    bf16* ctx   = (bf16*)(ws + off);  off += 2097152ull * 2;
    bf16* tmp   = (bf16*)(ws + off);  off += 2097152ull * 2;
    bf16* ffn   = (bf16*)(ws + off);  off += 8388608ull * 2;
    (void)ws_size; (void)in_sizes; (void)n_in; (void)out_size;

    float* out_h = (float*)d_out;
    float* out_attn = out_h + 2097152;

    TDesc td{};
    int tile = 0, e = 0;
    auto add = [&](const float* src, size_t dst, int K, int N) {
        td.m[e].src = src; td.m[e].dst = dst; td.m[e].K = K; td.m[e].N = N;
        td.m[e].tile0 = tile; tile += (K >> 5) * (N >> 5); ++e;
    };
    add(We, 0, 128, 512);
    for (int l = 0; l < 4; ++l) {
        size_t base = 65536 + (size_t)l * 3145728;
        add(Wq + (size_t)l * 262144,  base + 0,       512, 512);
        add(Wk + (size_t)l * 262144,  base + 262144,  512, 512);
        add(Wv + (size_t)l * 262144,  base + 524288,  512, 512);
        add(Wo + (size_t)l * 262144,  base + 786432,  512, 512);
        add(W1 + (size_t)l * 1048576, base + 1048576, 512, 2048);
        add(W2 + (size_t)l * 1048576, base + 2097152, 2048, 512);
    }
    td.m[e].tile0 = tile;  // sentinel (e == 25)

    wtrans_kernel<<<dim3(tile), dim3(256), 0, stream>>>(td, wbuf);
    prep_kernel<<<dim3(1048), dim3(256), 0, stream>>>(x, xbf, pe, bq, bk, bv, bqkv);

    // embed: hbf = bf16(x @ We + be + PE)
    gemm_kernel<64, 128, 2><<<dim3(256), dim3(256), 0, stream>>>(
        xbf, wbuf, be, hbf, pe, 128, 512, 4, 32);

    for (int l = 0; l < 4; ++l) {
        const bf16* WqkvT = wbuf + 65536 + (size_t)l * 3145728;
        const bf16* WoT   = WqkvT + 786432;
        const bf16* W1T   = WqkvT + 1048576;
        const bf16* W2T   = WqkvT + 2097152;
        for (int pass = 0; pass < 2; ++pass) {
            // qkv: 64x192 tiles -> grid 512 = even 2 blk/CU (was 384, 2:1)
            gemm_kernel<64, 192, 0><<<dim3(512), dim3(256), 0, stream>>>(
                hbf, WqkvT, bqkv + l * 1536, qkvb, (float*)nullptr,
                512, 1536, 8, 64);
            if (pass == 0)
                attn_kernel<0><<<dim3(8, 64), dim3(256), 0, stream>>>(
                    qkvb, ctx, (float*)nullptr);
            else
                attn_kernel<1><<<dim3(8, 64), dim3(256), 0, stream>>>(
                    qkvb, ctx, out_attn + (size_t)l * 2097152);
            gemm_kernel<64, 128, 0><<<dim3(256), dim3(256), 0, stream>>>(
                ctx, WoT, bo + l * 512, tmp, (float*)nullptr,
                512, 512, 4, 32);
            ln_kernel<<<dim3(1024), dim3(256), 0, stream>>>(
                tmp, hbf, g1 + l * 512, b1n + l * 512, hbf, (float*)nullptr);
        }
        gemm_kernel<128, 128, 1><<<dim3(512), dim3(256), 0, stream>>>(
            hbf, W1T, b1f + l * 2048, ffn, (float*)nullptr,
            512, 2048, 16, 64);
        gemm_kernel<64, 128, 0><<<dim3(256), dim3(256), 0, stream>>>(
            ffn, W2T, b2f + l * 512, tmp, (float*)nullptr,
            2048, 512, 4, 32);
        ln_kernel<<<dim3(1024), dim3(256), 0, stream>>>(
            tmp, hbf, g2 + l * 512, b2n + l * 512, hbf,
            (l == 3) ? out_h : (float*)nullptr);
    }
}

// Round 13
// 667.435 us; speedup vs baseline: 1.0474x; 1.0198x over previous
//
#include <hip/hip_runtime.h>

using bf16 = __bf16;
using bf16x8 = __attribute__((ext_vector_type(8))) __bf16;
using bf16x4 = __attribute__((ext_vector_type(4))) __bf16;
using f32x4  = __attribute__((ext_vector_type(4))) float;

#define AS1(p) ((const __attribute__((address_space(1))) unsigned int*)(p))
#define AS3(p) ((__attribute__((address_space(3))) unsigned int*)(p))

template<int N> __device__ __forceinline__ void wait_vmcnt() {
    if constexpr (N == 0) asm volatile("s_waitcnt vmcnt(0)" ::: "memory");
    else if constexpr (N == 3) asm volatile("s_waitcnt vmcnt(3)" ::: "memory");
    else if constexpr (N == 4) asm volatile("s_waitcnt vmcnt(4)" ::: "memory");
    else if constexpr (N == 6) asm volatile("s_waitcnt vmcnt(6)" ::: "memory");
    else if constexpr (N == 8) asm volatile("s_waitcnt vmcnt(8)" ::: "memory");
}

// ---------------------------------------------------------------------------
// bf16 MFMA GEMM: C[M,N] = A[M,K] @ WT[N,K]^T + bias
// Tile TM x TN, BK=32, 256 threads (4 waves, 2x2), fragments 16x16x32.
// TRIPLE-buffered LDS, depth-2 counted-vmcnt pipeline, k-XOR LDS swizzle.
// R13: exact R10-best geometry (qkv 128x128 grid 384 — R9/R11/R12 all showed
// every geometry perturbation of this structure loses; m102-curve confirmed).
// EPI: 0 = +bias, bf16; 1 = +bias, GELU, bf16; 2 = +bias+PE, bf16 (embed)
// ---------------------------------------------------------------------------
template<int TM, int TN, int EPI>
__global__ __launch_bounds__(256, TM == 64 ? 4 : 3)
void gemm_kernel(const bf16* __restrict__ A, const bf16* __restrict__ WT,
                 const float* __restrict__ bias, bf16* __restrict__ Cbf,
                 const float* __restrict__ PE,
                 int K, int ldc, int gx, int q8)
{
    constexpr int NA  = TM / 16;      // A staging chunks (16 rows x 32 k = 1KB)
    constexpr int NCH = NA + TN / 16; // + B chunks
    constexpr int CPW = NCH / 4;      // chunks per wave (3 or 4)
    constexpr int MI  = TM / 32;      // row fragments per wave
    constexpr int NI  = TN / 32;      // col fragments per wave
    constexpr int ASZ = TM * 32;
    constexpr int BSZ = TN * 32;
    __shared__ bf16 Asm[3 * ASZ];
    __shared__ bf16 Bsm[3 * BSZ];
    const int tid = threadIdx.x;
    const int lane = tid & 63;
    const int w  = tid >> 6;          // wave id 0..3 (wave-uniform)
    const int wr = w >> 1, wc = w & 1;
    const int l4 = lane & 15, lg = lane >> 4;

    // XCD-bijective swizzle: consecutive swizzled ids land on one XCD.
    const int bid = blockIdx.x;
    const int s  = (bid & 7) * q8 + (bid >> 3);
    const int by = s / gx, bx = s - by * gx;
    const size_t m0 = (size_t)by * TM;
    const size_t n0 = (size_t)bx * TN;

    f32x4 acc[MI][NI] = {};

    // staging: chunk c<NA -> A rows c*16.., else B rows (c-NA)*16..
    // source k pre-swizzled so LDS [row][kgrp] holds global [row][kgrp^g(row)]
    const int lr  = lane >> 2;                              // within-chunk row
    const int ksw = (((lane & 3) ^ ((lane >> 3) & 3)) * 8); // swizzled k start
    const bf16* src[CPW];
    bf16* dst0[CPW];
    int step[CPW];
    #pragma unroll
    for (int ci = 0; ci < CPW; ++ci) {
        const int c = w * CPW + ci;
        if (c < NA) {
            src[ci]  = A + (m0 + (size_t)(c * 16 + lr)) * K + ksw;
            dst0[ci] = Asm + c * 512;
            step[ci] = ASZ;
        } else {
            src[ci]  = WT + (n0 + (size_t)((c - NA) * 16 + lr)) * K + ksw;
            dst0[ci] = Bsm + (c - NA) * 512;
            step[ci] = BSZ;
        }
    }
    // read side: same XOR (invariant under +16-row stride and wr/wc offsets)
    const int rsw = (lg ^ ((l4 >> 1) & 3)) * 8;
    const bf16* Ar = &Asm[(wr * (TM / 2) + l4) * 32 + rsw];
    const bf16* Br = &Bsm[(wc * (TN / 2) + l4) * 32 + rsw];

    auto STAGE = [&](int b) {
        #pragma unroll
        for (int ci = 0; ci < CPW; ++ci) {
            __builtin_amdgcn_global_load_lds(AS1(src[ci]),
                                             AS3(dst0[ci] + b * step[ci]), 16, 0, 0);
            src[ci] += 32;
        }
    };

    const int nt = K >> 5;
    STAGE(0);
    if (nt > 1) STAGE(1);

    int cur = 0;
    for (int t = 0; t < nt; ++t) {
        if (t + 2 < nt) {
            int pb = cur - 1; if (pb < 0) pb = 2;   // (cur+2)%3
            STAGE(pb);
            wait_vmcnt<2 * CPW>();   // tile t done; t+1,t+2 stay in flight
        } else if (t + 1 < nt) {
            wait_vmcnt<CPW>();
        } else {
            wait_vmcnt<0>();
        }
        __builtin_amdgcn_s_barrier();       // (A) buf[cur] visible to all
        const bf16* Ac = Ar + cur * ASZ;
        const bf16* Bc = Br + cur * BSZ;
        bf16x8 aF[MI], bF[NI];
        #pragma unroll
        for (int i = 0; i < MI; ++i) aF[i] = *(const bf16x8*)(Ac + i * 512);
        #pragma unroll
        for (int i = 0; i < NI; ++i) bF[i] = *(const bf16x8*)(Bc + i * 512);
        #pragma unroll
        for (int mi = 0; mi < MI; ++mi)
            #pragma unroll
            for (int ni = 0; ni < NI; ++ni)
                acc[mi][ni] = __builtin_amdgcn_mfma_f32_16x16x32_bf16(
                    aF[mi], bF[ni], acc[mi][ni], 0, 0, 0);
        asm volatile("s_waitcnt lgkmcnt(0)" ::: "memory");  // reads retired
        __builtin_amdgcn_s_barrier();       // (B) all reads of cur done
        cur = (cur == 2) ? 0 : cur + 1;
    }

    #pragma unroll
    for (int ni = 0; ni < NI; ++ni) {
        const int col = (int)n0 + wc * (TN / 2) + ni * 16 + l4;
        const float bv = bias[col];
        #pragma unroll
        for (int mi = 0; mi < MI; ++mi) {
            const int row0 = (int)m0 + wr * (TM / 2) + mi * 16 + lg * 4;
            #pragma unroll
            for (int r = 0; r < 4; ++r) {
                float v = acc[mi][ni][r] + bv;
                const int row = row0 + r;
                if (EPI == 1) {
                    // GELU(tanh) == v * sigmoid(2*sqrt(2/pi)*(v+0.044715 v^3))
                    float u = 1.5957691216057308f * (v + 0.044715f * v * v * v);
                    v = v / (1.0f + __expf(-u));
                }
                if (EPI == 2) {
                    v += PE[((row & 511) << 9) + col];
                }
                Cbf[(size_t)row * ldc + col] = (bf16)v;
            }
        }
    }
}

// ---------------------------------------------------------------------------
// Fused band attention. 1D grid 512: bh = bid&63, ib = bid>>6 — all 8 row-tile
// blocks sharing one (b,h)'s K/V panel satisfy bid%8 == bh%8 -> same XCD (T1):
// each XCD holds 8 panels (1MB, L2-resident) with no cross-XCD duplication.
// 256 thr, 4 waves; wave w owns rows w*16..w*16+15 -> softmax wave-local.
// LDS: Ks unioned with Ps (Ks dead after QK^T; barrier closes the race) ->
// 53KB -> 3 blocks/CU. ctx staged through dead Vt for coalesced stores.
// qkv layout [4096][1536] (q|k|v each 512 cols). ctx layout [4096][512].
// WRITE_ATTN pass also zero-fills the out-of-band columns (replaces memset).
// ---------------------------------------------------------------------------
template<int WRITE_ATTN>
__global__ __launch_bounds__(256, 3)
void attn_kernel(const bf16* __restrict__ qkv, bf16* __restrict__ ctx,
                 float* __restrict__ attn_out /* already + l*2097152 */)
{
    __shared__ bf16 KPs[192 * 72];  // K rows stride 72; reused as P stride 200
    __shared__ bf16 Vt[64 * 200];   // V transposed [d][j]; reused for ctx tile
    bf16* Ks = KPs;
    bf16* Ps = KPs;                 // 64*200 = 12800 <= 13824 elems
    const int tid = threadIdx.x;
    const int lane = tid & 63, w = tid >> 6;
    const int l4 = lane & 15, lg = lane >> 4;
    const int bid = blockIdx.x;
    const int bh = bid & 63, ib = bid >> 6;
    const int b = bh >> 3, hd = bh & 7;
    const int i0 = ib * 64;
    const int j0 = (i0 >= 64) ? i0 - 64 : 0;
    const int j1 = (i0 + 128 <= 512) ? i0 + 128 : 512;
    const int W = j1 - j0;          // 128 or 192
    const size_t rowb = (size_t)b * 512;

    // zero out-of-band attention columns (replaces the global memset)
    if (WRITE_ATTN) {
        float* arow = attn_out + (size_t)b * 8388608 + (size_t)hd * 262144 +
                      (size_t)i0 * 512;
        const int zr = tid >> 2, p = tid & 3;
        f32x4 z = {0.f, 0.f, 0.f, 0.f};
        f32x4* rp = (f32x4*)(arow + (size_t)zr * 512);
        for (int c = p; c < (j0 >> 2); c += 4) rp[c] = z;
        for (int c = (j1 >> 2) + p; c < 128; c += 4) rp[c] = z;
    }

    // stage K rows [j0, j0+W)
    for (int it = 0; it < 6; ++it) {
        int chunk = tid + it * 256;                 // 0..1535
        int j = chunk >> 3, k0 = (chunk & 7) * 8;
        if (j < W) {
            bf16x8 v = *(const bf16x8*)(qkv + (rowb + j0 + j) * 1536 + 512 + hd * 64 + k0);
            *(bf16x8*)(&Ks[j * 72 + k0]) = v;
        }
    }
    // stage V transposed
    for (int it = 0; it < 6; ++it) {
        int chunk = tid + it * 256;
        int j = chunk >> 3, d0 = (chunk & 7) * 8;
        if (j < W) {
            bf16x8 v = *(const bf16x8*)(qkv + (rowb + j0 + j) * 1536 + 1024 + hd * 64 + d0);
            #pragma unroll
            for (int e = 0; e < 8; ++e) Vt[(d0 + e) * 200 + j] = v[e];
        }
    }
    // Q fragments for this wave's 16 rows, straight from global (L2-hot)
    bf16x8 qF0, qF1;
    {
        const bf16* qrow = qkv + (rowb + i0 + w * 16 + l4) * 1536 + hd * 64;
        qF0 = *(const bf16x8*)(qrow + lg * 8);
        qF1 = *(const bf16x8*)(qrow + 32 + lg * 8);
    }
    __syncthreads();

    // S = Q K^T / 8 over up to 12 col tiles
    f32x4 s[12];
    #pragma unroll
    for (int t = 0; t < 12; ++t) s[t] = (f32x4){0.f, 0.f, 0.f, 0.f};
    const int NT = W >> 4;
    __builtin_amdgcn_s_setprio(1);
    for (int t = 0; t < NT; ++t) {
        const bf16* kb = &Ks[(t * 16 + l4) * 72];
        bf16x8 b0 = *(const bf16x8*)(kb + lg * 8);
        bf16x8 b1 = *(const bf16x8*)(kb + 32 + lg * 8);
        s[t] = __builtin_amdgcn_mfma_f32_16x16x32_bf16(qF0, b0, s[t], 0, 0, 0);
        s[t] = __builtin_amdgcn_mfma_f32_16x16x32_bf16(qF1, b1, s[t], 0, 0, 0);
    }
    __builtin_amdgcn_s_setprio(0);
    // scale + band mask; row i = i0 + w*16 + lg*4 + r, col j = j0 + t*16 + l4
    const int irow0 = i0 + w * 16 + lg * 4;
    float pm[4] = {-3e38f, -3e38f, -3e38f, -3e38f};
    for (int t = 0; t < NT; ++t) {
        int jg = j0 + t * 16 + l4;
        #pragma unroll
        for (int r = 0; r < 4; ++r) {
            int dd = irow0 + r - jg;
            float sv = s[t][r] * 0.125f;
            if (dd > 64 || dd < -64) sv = -1e30f;
            s[t][r] = sv;
            pm[r] = fmaxf(pm[r], sv);
        }
    }
    #pragma unroll
    for (int d = 1; d < 16; d <<= 1)
        #pragma unroll
        for (int r = 0; r < 4; ++r) pm[r] = fmaxf(pm[r], __shfl_xor(pm[r], d));
    float ps[4] = {0.f, 0.f, 0.f, 0.f};
    for (int t = 0; t < NT; ++t)
        #pragma unroll
        for (int r = 0; r < 4; ++r) {
            float p = __expf(s[t][r] - pm[r]);
            s[t][r] = p;
            ps[r] += p;
        }
    #pragma unroll
    for (int d = 1; d < 16; d <<= 1)
        #pragma unroll
        for (int r = 0; r < 4; ++r) ps[r] += __shfl_xor(ps[r], d);
    float rinv[4];
    #pragma unroll
    for (int r = 0; r < 4; ++r) rinv[r] = 1.0f / ps[r];

    __syncthreads();    // all waves done reading Ks -> safe to write Ps union

    for (int t = 0; t < NT; ++t) {
        #pragma unroll
        for (int r = 0; r < 4; ++r) {
            float p = s[t][r] * rinv[r];
            Ps[(w * 16 + lg * 4 + r) * 200 + t * 16 + l4] = (bf16)p;
            if (WRITE_ATTN) {
                size_t off = (size_t)b * 8388608 + (size_t)hd * 262144 +
                             (size_t)(i0 + w * 16 + lg * 4 + r) * 512 +
                             (size_t)(j0 + t * 16 + l4);
                attn_out[off] = p;
            }
        }
    }
    // ctx = P @ V  (Ps rows are wave-private; compiler inserts lgkmcnt wait)
    f32x4 o[4] = {};
    const int KS = W >> 5;
    __builtin_amdgcn_s_setprio(1);
    for (int ks = 0; ks < KS; ++ks) {
        bf16x8 aF = *(const bf16x8*)(&Ps[(w * 16 + l4) * 200 + ks * 32 + lg * 8]);
        #pragma unroll
        for (int ni = 0; ni < 4; ++ni) {
            bf16x8 bF = *(const bf16x8*)(&Vt[(ni * 16 + l4) * 200 + ks * 32 + lg * 8]);
            o[ni] = __builtin_amdgcn_mfma_f32_16x16x32_bf16(aF, bF, o[ni], 0, 0, 0);
        }
    }
    __builtin_amdgcn_s_setprio(0);
    // stage ctx tile (64x64 bf16) into dead Vt, then coalesced bf16x8 stores
    __syncthreads();    // all waves done reading Vt/Ps
    bf16* Cs = Vt;
    #pragma unroll
    for (int ni = 0; ni < 4; ++ni)
        #pragma unroll
        for (int r = 0; r < 4; ++r)
            Cs[(w * 16 + lg * 4 + r) * 64 + ni * 16 + l4] = (bf16)o[ni][r];
    __syncthreads();
    #pragma unroll
    for (int it = 0; it < 2; ++it) {
        int chunk = tid + it * 256;
        int rl = chunk >> 3, c0 = (chunk & 7) << 3;
        *(bf16x8*)(&ctx[(rowb + i0 + rl) * 512 + hd * 64 + c0]) =
            *(const bf16x8*)(&Cs[rl * 64 + c0]);
    }
}

// ---------------------------------------------------------------------------
// LayerNorm(residual + y): wave per row (D=512, 8 elems/lane).
// Residual stream is bf16-only (stats/normalization still f32 in-reg).
// hf==nullptr -> write bf16 hbf (in-place safe, block owns its rows);
// hf!=nullptr -> final layer, write f32 output only.
// ---------------------------------------------------------------------------
__global__ __launch_bounds__(256)
void ln_kernel(const bf16* __restrict__ y, const bf16* __restrict__ hin,
               const float* __restrict__ g, const float* __restrict__ bb,
               bf16* __restrict__ hbf, float* __restrict__ hf)
{
    const int row = blockIdx.x * 4 + (threadIdx.x >> 6);
    const int lane = threadIdx.x & 63;
    const size_t base = (size_t)row * 512 + lane * 8;
    bf16x8 yv = *(const bf16x8*)(y + base);
    bf16x8 hv = *(const bf16x8*)(hin + base);
    float x[8];
    #pragma unroll
    for (int i = 0; i < 8; ++i) x[i] = (float)yv[i] + (float)hv[i];
    float s = 0.f, q = 0.f;
    #pragma unroll
    for (int i = 0; i < 8; ++i) { s += x[i]; q += x[i] * x[i]; }
    #pragma unroll
    for (int d = 1; d < 64; d <<= 1) { s += __shfl_xor(s, d); q += __shfl_xor(q, d); }
    const float m = s * 0.001953125f;
    const float var = q * 0.001953125f - m * m;
    const float rstd = rsqrtf(var + 1e-5f);
    const int c0 = lane * 8;
    f32x4 g0 = *(const f32x4*)(g + c0), g1v = *(const f32x4*)(g + c0 + 4);
    f32x4 b0 = *(const f32x4*)(bb + c0), b1v = *(const f32x4*)(bb + c0 + 4);
    float o[8];
    #pragma unroll
    for (int i = 0; i < 8; ++i) {
        float gg = i < 4 ? g0[i] : g1v[i - 4];
        float bv = i < 4 ? b0[i] : b1v[i - 4];
        o[i] = (x[i] - m) * rstd * gg + bv;
    }
    if (hf) {
        f32x4 o0, o1;
        #pragma unroll
        for (int i = 0; i < 4; ++i) { o0[i] = o[i]; o1[i] = o[i + 4]; }
        *(f32x4*)(hf + base) = o0;
        *(f32x4*)(hf + base + 4) = o1;
    } else {
        bf16x8 ob;
        #pragma unroll
        for (int i = 0; i < 8; ++i) ob[i] = (bf16)o[i];
        *(bf16x8*)(hbf + base) = ob;
    }
}

// ---------------------------------------------------------------------------
// Weight transpose+convert: src f32 [K][N] -> dst bf16 [N][K] (32x32 LDS tiles)
// ---------------------------------------------------------------------------
struct TMat { const float* src; size_t dst; int K; int N; int tile0; };
struct TDesc { TMat m[26]; };

__global__ __launch_bounds__(256)
void wtrans_kernel(TDesc d, bf16* __restrict__ wbuf)
{
    __shared__ float tile[32][33];
    int t = blockIdx.x;
    int mi = 0;
    while (t >= d.m[mi + 1].tile0) ++mi;
    const TMat mm = d.m[mi];
    const int lt = t - mm.tile0;
    const int tpr = mm.N >> 5;
    const int kt = lt / tpr, nt = lt % tpr;
    const int r = threadIdx.x >> 5, c = threadIdx.x & 31;
    #pragma unroll
    for (int it = 0; it < 4; ++it)
        tile[r + it * 8][c] =
            mm.src[(size_t)(kt * 32 + r + it * 8) * mm.N + nt * 32 + c];
    __syncthreads();
    #pragma unroll
    for (int it = 0; it < 4; ++it)
        wbuf[mm.dst + (size_t)(nt * 32 + r + it * 8) * mm.K + kt * 32 + c] =
            (bf16)tile[c][r + it * 8];
}

// ---------------------------------------------------------------------------
// Fused prep: blocks 0-511 f2bf(x), 512-1023 PE table, 1024-1047 bias concat
// ---------------------------------------------------------------------------
__global__ void prep_kernel(const float* __restrict__ x, bf16* __restrict__ xbf,
                            float* __restrict__ pe,
                            const float* bq, const float* bk, const float* bv,
                            float* __restrict__ bqkv)
{
    const int bid = blockIdx.x;
    if (bid < 512) {
        int i = bid * 256 + threadIdx.x;       // 131072 vec4
        f32x4 v = *(const f32x4*)(x + (size_t)i * 4);
        bf16x4 o;
        #pragma unroll
        for (int e = 0; e < 4; ++e) o[e] = (bf16)v[e];
        *(bf16x4*)(xbf + (size_t)i * 4) = o;
    } else if (bid < 1024) {
        int i = (bid - 512) * 256 + threadIdx.x;   // 131072 (s,d2) pairs
        int s = i >> 8, d2 = i & 255;
        float ang = (float)s * expf((float)(2 * d2) * -0.017988946039016f);
        pe[(s << 9) + 2 * d2]     = sinf(ang);
        pe[(s << 9) + 2 * d2 + 1] = cosf(ang);
    } else {
        int i = (bid - 1024) * 256 + threadIdx.x;  // 6144
        if (i < 6144) {
            int l = i / 1536, c = i - l * 1536;
            float v;
            if (c < 512) v = bq[l * 512 + c];
            else if (c < 1024) v = bk[l * 512 + c - 512];
            else v = bv[l * 512 + c - 1024];
            bqkv[i] = v;
        }
    }
}

// ---------------------------------------------------------------------------
extern "C" void kernel_launch(void* const* d_in, const int* in_sizes, int n_in,
                              void* d_out, int out_size, void* d_ws, size_t ws_size,
                              hipStream_t stream)
{
    const float* x   = (const float*)d_in[0];
    const float* We  = (const float*)d_in[1];
    const float* be  = (const float*)d_in[2];
    const float* Wq  = (const float*)d_in[3];
    const float* bq  = (const float*)d_in[4];
    const float* Wk  = (const float*)d_in[5];
    const float* bk  = (const float*)d_in[6];
    const float* Wv  = (const float*)d_in[7];
    const float* bv  = (const float*)d_in[8];
    const float* Wo  = (const float*)d_in[9];
    const float* bo  = (const float*)d_in[10];
    const float* g1  = (const float*)d_in[11];
    const float* b1n = (const float*)d_in[12];
    const float* W1  = (const float*)d_in[13];
    const float* b1f = (const float*)d_in[14];
    const float* W2  = (const float*)d_in[15];
    const float* b2f = (const float*)d_in[16];
    const float* g2  = (const float*)d_in[17];
    const float* b2n = (const float*)d_in[18];

    char* ws = (char*)d_ws;
    bf16* wbuf = (bf16*)ws;
    size_t off = 12648448ull * 2;                       // transposed bf16 weights
    float* bqkv = (float*)(ws + off); off += 6144ull * 4;
    float* pe   = (float*)(ws + off); off += 262144ull * 4;
    bf16* xbf   = (bf16*)(ws + off);  off += 524288ull * 2;
    bf16* hbf   = (bf16*)(ws + off);  off += 2097152ull * 2;
    bf16* qkvb  = (bf16*)(ws + off);  off += 6291456ull * 2;
    bf16* ctx   = (bf16*)(ws + off);  off += 2097152ull * 2;
    bf16* tmp   = (bf16*)(ws + off);  off += 2097152ull * 2;
    bf16* ffn   = (bf16*)(ws + off);  off += 8388608ull * 2;
    (void)ws_size; (void)in_sizes; (void)n_in; (void)out_size;

    float* out_h = (float*)d_out;
    float* out_attn = out_h + 2097152;

    TDesc td{};
    int tile = 0, e = 0;
    auto add = [&](const float* src, size_t dst, int K, int N) {
        td.m[e].src = src; td.m[e].dst = dst; td.m[e].K = K; td.m[e].N = N;
        td.m[e].tile0 = tile; tile += (K >> 5) * (N >> 5); ++e;
    };
    add(We, 0, 128, 512);
    for (int l = 0; l < 4; ++l) {
        size_t base = 65536 + (size_t)l * 3145728;
        add(Wq + (size_t)l * 262144,  base + 0,       512, 512);
        add(Wk + (size_t)l * 262144,  base + 262144,  512, 512);
        add(Wv + (size_t)l * 262144,  base + 524288,  512, 512);
        add(Wo + (size_t)l * 262144,  base + 786432,  512, 512);
        add(W1 + (size_t)l * 1048576, base + 1048576, 512, 2048);
        add(W2 + (size_t)l * 1048576, base + 2097152, 2048, 512);
    }
    td.m[e].tile0 = tile;  // sentinel (e == 25)

    wtrans_kernel<<<dim3(tile), dim3(256), 0, stream>>>(td, wbuf);
    prep_kernel<<<dim3(1048), dim3(256), 0, stream>>>(x, xbf, pe, bq, bk, bv, bqkv);

    // embed: hbf = bf16(x @ We + be + PE)
    gemm_kernel<64, 128, 2><<<dim3(256), dim3(256), 0, stream>>>(
        xbf, wbuf, be, hbf, pe, 128, 512, 4, 32);

    for (int l = 0; l < 4; ++l) {
        const bf16* WqkvT = wbuf + 65536 + (size_t)l * 3145728;
        const bf16* WoT   = WqkvT + 786432;
        const bf16* W1T   = WqkvT + 1048576;
        const bf16* W2T   = WqkvT + 2097152;
        for (int pass = 0; pass < 2; ++pass) {
            gemm_kernel<128, 128, 0><<<dim3(384), dim3(256), 0, stream>>>(
                hbf, WqkvT, bqkv + l * 1536, qkvb, (float*)nullptr,
                512, 1536, 12, 48);
            if (pass == 0)
                attn_kernel<0><<<dim3(512), dim3(256), 0, stream>>>(
                    qkvb, ctx, (float*)nullptr);
            else
                attn_kernel<1><<<dim3(512), dim3(256), 0, stream>>>(
                    qkvb, ctx, out_attn + (size_t)l * 2097152);
            gemm_kernel<64, 128, 0><<<dim3(256), dim3(256), 0, stream>>>(
                ctx, WoT, bo + l * 512, tmp, (float*)nullptr,
                512, 512, 4, 32);
            ln_kernel<<<dim3(1024), dim3(256), 0, stream>>>(
                tmp, hbf, g1 + l * 512, b1n + l * 512, hbf, (float*)nullptr);
        }
        gemm_kernel<128, 128, 1><<<dim3(512), dim3(256), 0, stream>>>(
            hbf, W1T, b1f + l * 2048, ffn, (float*)nullptr,
            512, 2048, 16, 64);
        gemm_kernel<64, 128, 0><<<dim3(256), dim3(256), 0, stream>>>(
            ffn, W2T, b2f + l * 512, tmp, (float*)nullptr,
            2048, 512, 4, 32);
        ln_kernel<<<dim3(1024), dim3(256), 0, stream>>>(
            tmp, hbf, g2 + l * 512, b2n + l * 512, hbf,
            (l == 3) ? out_h : (float*)nullptr);
    }
}